// Round 4
// baseline (403.942 us; speedup 1.0000x reference)
//
#include <hip/hip_runtime.h>
#include <hip/hip_bf16.h>
#include <math.h>

#define B_ 2
#define T_ 2048
#define C_ 2048
#define H_ 16
#define KVH_ 4
#define HD_ 128
#define G_ (H_ / KVH_)
#define MROWS (B_ * T_)                    // 4096
#define NQKV (H_ * HD_ + 2 * KVH_ * HD_)   // 3072
#define KOFF (H_ * HD_)                    // 2048
#define VOFF (H_ * HD_ + KVH_ * HD_)       // 2560

typedef __hip_bfloat16 bf16;
typedef short bf16x8 __attribute__((ext_vector_type(8)));   // 8 bf16 = 4 VGPR
typedef short bf16x4 __attribute__((ext_vector_type(4)));   // 4 bf16 = 2 VGPR
typedef float f32x4 __attribute__((ext_vector_type(4)));

__device__ __forceinline__ void gload_lds16(const void* g, void* l) {
  __builtin_amdgcn_global_load_lds(
      (const __attribute__((address_space(1))) unsigned int*)g,
      (__attribute__((address_space(3))) unsigned int*)l, 16, 0, 0);
}

static __device__ __forceinline__ f32x4 mfma16(bf16x4 a, bf16x4 b, f32x4 c) {
#if __has_builtin(__builtin_amdgcn_mfma_f32_16x16x16_bf16)
  return __builtin_amdgcn_mfma_f32_16x16x16_bf16(a, b, c, 0, 0, 0);
#else
  return __builtin_amdgcn_mfma_f32_16x16x16bf16_1k(a, b, c, 0, 0, 0);
#endif
}

// fast RNE f32->bf16 (no NaN handling; inputs are finite probabilities/sums)
static __device__ __forceinline__ short f2bf(float x) {
  unsigned u = __builtin_bit_cast(unsigned, x);
  u += 0x7FFFu + ((u >> 16) & 1u);
  return (short)(u >> 16);
}

static __device__ __forceinline__ float fexp2(float x) {
#if __has_builtin(__builtin_amdgcn_exp2f)
  return __builtin_amdgcn_exp2f(x);
#else
  return exp2f(x);
#endif
}

// ---------------------------------------------------------------------------
// fp32 -> bf16 elementwise cast
// ---------------------------------------------------------------------------
__global__ void cast_bf16_kernel(const float* __restrict__ in, bf16* __restrict__ out, int n) {
  int i = (blockIdx.x * 256 + threadIdx.x) * 4;
  if (i >= n) return;
  float4 v = *(const float4*)(in + i);
  out[i + 0] = __float2bfloat16(v.x);
  out[i + 1] = __float2bfloat16(v.y);
  out[i + 2] = __float2bfloat16(v.z);
  out[i + 3] = __float2bfloat16(v.w);
}

// ---------------------------------------------------------------------------
// fp32 [R][Ccols] -> bf16 out[Ccols][R]
// ---------------------------------------------------------------------------
__global__ __launch_bounds__(256) void transpose_cast(const float* __restrict__ in,
                                                      bf16* __restrict__ out,
                                                      int R, int Ccols) {
  __shared__ float t[32][33];
  const int tx = threadIdx.x & 31, ty = threadIdx.x >> 5;
  const int r0 = blockIdx.y * 32, c0 = blockIdx.x * 32;
#pragma unroll
  for (int it = 0; it < 4; ++it)
    t[ty + 8 * it][tx] = in[(size_t)(r0 + ty + 8 * it) * Ccols + c0 + tx];
  __syncthreads();
#pragma unroll
  for (int it = 0; it < 4; ++it)
    out[(size_t)(c0 + ty + 8 * it) * R + r0 + tx] = __float2bfloat16(t[tx][ty + 8 * it]);
}

// ---------------------------------------------------------------------------
// v half of qkv -> vt[((b*KVH+kvh)*HD + hd)*T + t]
// ---------------------------------------------------------------------------
__global__ __launch_bounds__(256) void transpose_v(const bf16* __restrict__ qkv,
                                                   bf16* __restrict__ vt) {
  __shared__ bf16 t[32][33];
  const int tx = threadIdx.x & 31, ty = threadIdx.x >> 5;
  const int b = blockIdx.z >> 2, kvh = blockIdx.z & 3;
  const int t0 = blockIdx.x * 32, d0 = blockIdx.y * 32;
#pragma unroll
  for (int it = 0; it < 4; ++it)
    t[ty + 8 * it][tx] =
        qkv[(size_t)(b * T_ + t0 + ty + 8 * it) * NQKV + VOFF + kvh * HD_ + d0 + tx];
  __syncthreads();
#pragma unroll
  for (int it = 0; it < 4; ++it)
    vt[((size_t)((b * KVH_ + kvh) * HD_) + d0 + ty + 8 * it) * T_ + t0 + tx] =
        t[tx][ty + 8 * it];
}

// ---------------------------------------------------------------------------
// RoPE in place on bf16 head-rows inside qkv.
// ---------------------------------------------------------------------------
__global__ void rope_bf16(bf16* __restrict__ buf, int ld, int col0, int nheads) {
  const int row = blockIdx.x / nheads;
  const int h = blockIdx.x % nheads;
  const int t = row % T_;
  const int d = threadIdx.x;
  bf16* rp = buf + (size_t)row * ld + col0 + h * HD_;
  float vd = __bfloat162float(rp[d]);
  float vp = __bfloat162float(rp[d ^ 64]);
  __syncthreads();
  const int i = d & 63;
  float invf = expf(-(float)(2 * i) * (9.210340371976184f / 128.0f));
  float ang = (float)t * invf;
  float c = cosf(ang), s = sinf(ang);
  rp[d] = __float2bfloat16((d < 64) ? (vd * c - vp * s) : (vd * c + vp * s));
}

// ---------------------------------------------------------------------------
// bf16 MFMA GEMM (m97 structure): C[M,N] = A[M,K] @ Bt[N,K]^T (+ bias)
// ---------------------------------------------------------------------------
template <bool BF16OUT>
__global__ __launch_bounds__(256, 2) void gemm_mfma(
    const bf16* __restrict__ A, const bf16* __restrict__ Bt, void* __restrict__ Cout,
    const float* __restrict__ bq, const float* __restrict__ bk2,
    const float* __restrict__ bv2, int M, int N, int K) {
  __shared__ __align__(16) bf16 As[128 * 32];
  __shared__ __align__(16) bf16 Bs[128 * 32];
  const int tid = threadIdx.x;
  const int w = tid >> 6, lane = tid & 63;
  const int colL = lane & 15, quad = lane >> 4;
  const int wm = w & 1, wn = w >> 1;
  const int r0 = blockIdx.y * 128, c0 = blockIdx.x * 128;

  f32x4 acc[4][4];
  const f32x4 zero = {0.f, 0.f, 0.f, 0.f};
#pragma unroll
  for (int mt = 0; mt < 4; ++mt)
#pragma unroll
    for (int nt = 0; nt < 4; ++nt) acc[mt][nt] = zero;

  for (int k0 = 0; k0 < K; k0 += 32) {
    __syncthreads();
#pragma unroll
    for (int it = 0; it < 2; ++it) {
      const int seg = it * 4 + w;
      const int idx = seg * 64 + lane;
      const int row = idx >> 2, off = idx & 3;
      gload_lds16(A + (size_t)(r0 + row) * K + k0 + off * 8, &As[seg * 512]);
      gload_lds16(Bt + (size_t)(c0 + row) * K + k0 + off * 8, &Bs[seg * 512]);
    }
    __syncthreads();
    bf16x8 af[4], bfv[4];
#pragma unroll
    for (int mt = 0; mt < 4; ++mt)
      af[mt] = *(const bf16x8*)&As[(wm * 64 + mt * 16 + colL) * 32 + quad * 8];
#pragma unroll
    for (int nt = 0; nt < 4; ++nt)
      bfv[nt] = *(const bf16x8*)&Bs[(wn * 64 + nt * 16 + colL) * 32 + quad * 8];
#pragma unroll
    for (int mt = 0; mt < 4; ++mt)
#pragma unroll
      for (int nt = 0; nt < 4; ++nt)
        acc[mt][nt] =
            __builtin_amdgcn_mfma_f32_16x16x32_bf16(af[mt], bfv[nt], acc[mt][nt], 0, 0, 0);
  }

#pragma unroll
  for (int nt = 0; nt < 4; ++nt) {
    const int c = c0 + wn * 64 + nt * 16 + colL;
    float bias = 0.f;
    if (bq) bias = (c < KOFF) ? bq[c] : (c < VOFF ? bk2[c - KOFF] : bv2[c - VOFF]);
#pragma unroll
    for (int mt = 0; mt < 4; ++mt) {
#pragma unroll
      for (int i = 0; i < 4; ++i) {
        const int r = r0 + wm * 64 + mt * 16 + quad * 4 + i;
        const float v = acc[mt][nt][i] + bias;
        if (BF16OUT)
          ((bf16*)Cout)[(size_t)r * N + c] = __float2bfloat16(v);
        else
          ((float*)Cout)[(size_t)r * N + c] = v;
      }
    }
  }
}

// ---------------------------------------------------------------------------
// Causal GQA flash attention v3.
// Block = 256 thr = 4 waves (qh = w>>1 selects 64-q half, p = w&1 selects kv
// tile parity). Q staged in LDS (32KB, XOR-swizzled). K/V double-buffered
// 2x16KB, staged cooperatively; raw s_barrier + per-wave vmcnt(0) one full
// compute phase after issue (prefetch stays in flight, no drain-at-issue).
// Transposed math (verified r3): S^T = K·Q^T; O^T = V^T·P^T, P in registers.
// Fixed-max softmax -> parity merge = pure (O,l) add via LDS.
// Grid: 512 1D blocks; ID mapping pairs heavy+light q-tiles so the 2 blocks
// co-resident on a CU sum to ~constant work.
// ---------------------------------------------------------------------------
#define FA_SCL2 (0.08838834764831845f * 1.4426950408889634f)  // scale * log2(e)
#define FA_M2 16.0f                                           // fixed max (exp2 domain)

__global__ __launch_bounds__(256, 2) void flash_mfma3(
    const bf16* __restrict__ qkv, const bf16* __restrict__ vt, bf16* __restrict__ ao) {
  __shared__ __align__(16) char smem[66048];
  bf16* Qs = (bf16*)smem;                        // [128 q][128 hd] swizzled, 32KB
  bf16* Kb0 = (bf16*)(smem + 32768);             // 8KB  [32 key][128 hd] swz
  bf16* Kb1 = (bf16*)(smem + 40960);             // 8KB
  bf16* Vb0 = (bf16*)(smem + 49152);             // 8KB  [128 hd][32 key] swz
  bf16* Vb1 = (bf16*)(smem + 57344);             // 8KB
  float* ob = (float*)smem;                      // merge scratch [64][132] f32 (overlaps Qs/Kb0; dead then)
  float* lb = (float*)(smem + 65536);            // 64 f32

  const int id = blockIdx.x;
  const int hbid = id >> 4;                      // 0..31
  const int qq = id & 15;
  const int qt = (hbid < 16) ? (15 - qq) : qq;   // complementary pairing across halves
  const int h = hbid & 15, b = hbid >> 4;
  const int kvh = h >> 2;
  const int q0 = qt * 128;

  const int tid = threadIdx.x;
  const int w = tid >> 6, lane = tid & 63;
  const int colL = lane & 15, quad = lane >> 4;
  const int qh = w >> 1, p = w & 1;
  const int myq0 = q0 + qh * 64;                 // this wave's 64-row q base (global)

  const bf16* kg = qkv + (size_t)(b * T_) * NQKV + KOFF + kvh * HD_;
  const bf16* vg = vt + (size_t)((b * KVH_ + kvh) * HD_) * T_;
  const bf16* qg = qkv + (size_t)(b * T_ + q0) * NQKV + h * HD_;

  // stage KV tile -> buffer bi (4 gload per wave: K segs 2w..2w+1, V segs 2w..2w+1)
  auto stageKV = [&](int tile, bf16* kl, bf16* vl) {
    const int s0k = tile * 32;
#pragma unroll
    for (int j = 0; j < 2; ++j) {
      const int s = 2 * w + j;
      const int row = s * 4 + quad;              // key 0..31
      const int g = colL ^ (row & 7);
      gload_lds16(kg + (size_t)(s0k + row) * NQKV + g * 8, kl + s * 512);
    }
#pragma unroll
    for (int j = 0; j < 2; ++j) {
      const int s = 2 * w + j;
      const int row = s * 16 + (lane >> 2);      // hd 0..127
      const int g = (lane & 3) ^ ((row >> 1) & 3);
      gload_lds16(vg + (size_t)row * T_ + s0k + g * 8, vl + s * 512);
    }
  };

  // stage Q (my 8 of 32 segs; same row-chunk swizzle as K)
#pragma unroll
  for (int s8 = 0; s8 < 8; ++s8) {
    const int s = w * 8 + s8;
    const int row = s * 4 + quad;                // q row 0..127 (local)
    const int g = colL ^ (row & 7);
    gload_lds16(qg + (size_t)row * NQKV + g * 8, Qs + s * 512);
  }
  stageKV(0, Kb0, Vb0);
  asm volatile("s_waitcnt vmcnt(0)\n\ts_barrier" ::: "memory");

  f32x4 o[4][8];  // O^T: lane holds (hd = ht*16 + quad*4 + i, q = myq0 + mq*16 + colL)
  const f32x4 zero = {0.f, 0.f, 0.f, 0.f};
#pragma unroll
  for (int mq = 0; mq < 4; ++mq)
#pragma unroll
    for (int ht = 0; ht < 8; ++ht) o[mq][ht] = zero;
  float l_[4] = {0.f, 0.f, 0.f, 0.f};

  const int nkv = 4 * qt + 4;
  for (int tt = 0; tt < nkv; ++tt) {
    const bf16* Ks = (tt & 1) ? Kb1 : Kb0;
    const bf16* Vs = (tt & 1) ? Vb1 : Vb0;
    if (tt + 1 < nkv) stageKV(tt + 1, (tt & 1) ? Kb0 : Kb1, (tt & 1) ? Vb0 : Vb1);

    const int s0 = tt * 32;
    if (((tt & 1) == p) && (s0 < myq0 + 64)) {
      // S^T = K · Q^T
      f32x4 s_[2][4];
#pragma unroll
      for (int kt = 0; kt < 2; ++kt)
#pragma unroll
        for (int mq = 0; mq < 4; ++mq) s_[kt][mq] = zero;
#pragma unroll
      for (int c = 0; c < 4; ++c) {
        const int ch = ((c * 4 + quad) ^ (colL & 7)) * 8;
        bf16x8 kf0 = *(const bf16x8*)(Ks + (size_t)colL * 128 + ch);
        bf16x8 kf1 = *(const bf16x8*)(Ks + (size_t)(16 + colL) * 128 + ch);
#pragma unroll
        for (int mq = 0; mq < 4; ++mq) {
          bf16x8 qf = *(const bf16x8*)(Qs + (size_t)(qh * 64 + mq * 16 + colL) * 128 + ch);
          s_[0][mq] = __builtin_amdgcn_mfma_f32_16x16x32_bf16(kf0, qf, s_[0][mq], 0, 0, 0);
          s_[1][mq] = __builtin_amdgcn_mfma_f32_16x16x32_bf16(kf1, qf, s_[1][mq], 0, 0, 0);
        }
      }

      // p = exp2(s*scale*log2e - M2); mask only on diagonal-straddling tiles
      bf16x4 pf[2][4];
      if (s0 >= myq0) {
#pragma unroll
        for (int kt = 0; kt < 2; ++kt)
#pragma unroll
          for (int mq = 0; mq < 4; ++mq) {
            const int qcol = myq0 + mq * 16 + colL;
            const int kb = s0 + kt * 16 + quad * 4;
            float pv[4];
#pragma unroll
            for (int i = 0; i < 4; ++i) {
              float e = fexp2(fmaf(s_[kt][mq][i], FA_SCL2, -FA_M2));
              pv[i] = (kb + i <= qcol) ? e : 0.f;
            }
            l_[mq] += (pv[0] + pv[1]) + (pv[2] + pv[3]);
            pf[kt][mq] = (bf16x4){f2bf(pv[0]), f2bf(pv[1]), f2bf(pv[2]), f2bf(pv[3])};
          }
      } else {
#pragma unroll
        for (int kt = 0; kt < 2; ++kt)
#pragma unroll
          for (int mq = 0; mq < 4; ++mq) {
            float pv[4];
#pragma unroll
            for (int i = 0; i < 4; ++i)
              pv[i] = fexp2(fmaf(s_[kt][mq][i], FA_SCL2, -FA_M2));
            l_[mq] += (pv[0] + pv[1]) + (pv[2] + pv[3]);
            pf[kt][mq] = (bf16x4){f2bf(pv[0]), f2bf(pv[1]), f2bf(pv[2]), f2bf(pv[3])};
          }
      }

      // O^T += V^T · P^T (P stays in registers)
#pragma unroll
      for (int ht = 0; ht < 8; ++ht) {
        const int row = ht * 16 + colL;
#pragma unroll
        for (int kt = 0; kt < 2; ++kt) {
          bf16x4 vf = *(const bf16x4*)(Vs + (size_t)row * 32 +
                                       (((kt * 2 + (quad >> 1)) ^ ((row >> 1) & 3)) * 8) +
                                       (quad & 1) * 4);
#pragma unroll
          for (int mq = 0; mq < 4; ++mq) o[mq][ht] = mfma16(vf, pf[kt][mq], o[mq][ht]);
        }
      }
    }
    // own 4 staging loads done (issued one compute-phase ago) + all waves synced
    asm volatile("s_waitcnt vmcnt(0)\n\ts_barrier" ::: "memory");
  }

  // reduce l over key-quads (within lane groups of same colL)
#pragma unroll
  for (int mq = 0; mq < 4; ++mq) {
    l_[mq] += __shfl_xor(l_[mq], 16);
    l_[mq] += __shfl_xor(l_[mq], 32);
  }

  // merge kv-parity pairs: (O,l) pure add (fixed max). Two sequential rounds
  // (qh=0 then qh=1) reusing the dead Q/K LDS as f32 scratch.
  __syncthreads();
#pragma unroll
  for (int r = 0; r < 2; ++r) {
    if (w == r * 2 + 1) {
#pragma unroll
      for (int mq = 0; mq < 4; ++mq) {
#pragma unroll
        for (int ht = 0; ht < 8; ++ht)
          *(f32x4*)&ob[(size_t)(mq * 16 + colL) * 132 + ht * 16 + quad * 4] = o[mq][ht];
        if (quad == 0) lb[mq * 16 + colL] = l_[mq];
      }
    }
    __syncthreads();
    if (w == r * 2) {
#pragma unroll
      for (int mq = 0; mq < 4; ++mq) {
        const float lt = l_[mq] + lb[mq * 16 + colL];
        const float rl = 1.f / lt;
        const size_t rbase = (size_t)(b * T_ + myq0 + mq * 16 + colL) * (H_ * HD_) + h * HD_;
#pragma unroll
        for (int ht = 0; ht < 8; ++ht) {
          f32x4 oo = o[mq][ht] + *(const f32x4*)&ob[(size_t)(mq * 16 + colL) * 132 + ht * 16 + quad * 4];
          bf16x4 ov;
#pragma unroll
          for (int i = 0; i < 4; ++i) ov[i] = f2bf(oo[i] * rl);
          *(bf16x4*)(ao + rbase + ht * 16 + quad * 4) = ov;
        }
      }
    }
    __syncthreads();
  }
}

// ---------------------------------------------------------------------------
extern "C" void kernel_launch(void* const* d_in, const int* in_sizes, int n_in,
                              void* d_out, int out_size, void* d_ws, size_t ws_size,
                              hipStream_t stream) {
  (void)in_sizes; (void)n_in; (void)out_size; (void)ws_size;
  const float* x  = (const float*)d_in[0];
  const float* wq = (const float*)d_in[1];
  const float* bq = (const float*)d_in[2];
  const float* wk = (const float*)d_in[3];
  const float* bk = (const float*)d_in[4];
  const float* wv = (const float*)d_in[5];
  const float* bv = (const float*)d_in[6];
  const float* wo = (const float*)d_in[7];
  float* out = (float*)d_out;

  char* ws = (char*)d_ws;
  bf16* xb    = (bf16*)ws;                 // 16 MiB; reused as ao after QKV gemm
  bf16* wqkvT = (bf16*)(ws + (16u << 20)); // 12 MiB [3072][2048]
  bf16* woT   = (bf16*)(ws + (28u << 20)); //  8 MiB [2048][2048]
  bf16* qkv   = (bf16*)(ws + (36u << 20)); // 24 MiB [4096][3072]
  bf16* vt    = (bf16*)(ws + (60u << 20)); //  4 MiB [1024][2048]

  cast_bf16_kernel<<<dim3(MROWS * C_ / 1024), dim3(256), 0, stream>>>(x, xb, MROWS * C_);

  transpose_cast<<<dim3(64, 64), dim3(256), 0, stream>>>(wq, wqkvT, C_, 2048);
  transpose_cast<<<dim3(16, 64), dim3(256), 0, stream>>>(wk, wqkvT + (size_t)KOFF * C_, C_, 512);
  transpose_cast<<<dim3(16, 64), dim3(256), 0, stream>>>(wv, wqkvT + (size_t)VOFF * C_, C_, 512);
  transpose_cast<<<dim3(64, 64), dim3(256), 0, stream>>>(wo, woT, 2048, 2048);

  gemm_mfma<true><<<dim3(NQKV / 128, MROWS / 128), dim3(256), 0, stream>>>(
      xb, wqkvT, qkv, bq, bk, bv, MROWS, NQKV, C_);

  rope_bf16<<<dim3(MROWS * H_), dim3(128), 0, stream>>>(qkv, NQKV, 0, H_);
  rope_bf16<<<dim3(MROWS * KVH_), dim3(128), 0, stream>>>(qkv, NQKV, KOFF, KVH_);

  transpose_v<<<dim3(T_ / 32, HD_ / 32, B_ * KVH_), dim3(256), 0, stream>>>(qkv, vt);

  bf16* ao = xb;
  flash_mfma3<<<dim3(512), dim3(256), 0, stream>>>(qkv, vt, ao);

  gemm_mfma<false><<<dim3(C_ / 128, MROWS / 128), dim3(256), 0, stream>>>(
      ao, woT, out, nullptr, nullptr, nullptr, MROWS, C_, KOFF);
}

// Round 5
// 358.766 us; speedup vs baseline: 1.1259x; 1.1259x over previous
//
#include <hip/hip_runtime.h>
#include <hip/hip_bf16.h>
#include <math.h>

#define B_ 2
#define T_ 2048
#define C_ 2048
#define H_ 16
#define KVH_ 4
#define HD_ 128
#define G_ (H_ / KVH_)
#define MROWS (B_ * T_)                    // 4096
#define NQKV (H_ * HD_ + 2 * KVH_ * HD_)   // 3072
#define KOFF (H_ * HD_)                    // 2048
#define VOFF (H_ * HD_ + KVH_ * HD_)       // 2560

typedef __hip_bfloat16 bf16;
typedef short bf16x8 __attribute__((ext_vector_type(8)));   // 8 bf16 = 4 VGPR
typedef short bf16x4 __attribute__((ext_vector_type(4)));   // 4 bf16 = 2 VGPR
typedef float f32x4 __attribute__((ext_vector_type(4)));

__device__ __forceinline__ void gload_lds16(const void* g, void* l) {
  __builtin_amdgcn_global_load_lds(
      (const __attribute__((address_space(1))) unsigned int*)g,
      (__attribute__((address_space(3))) unsigned int*)l, 16, 0, 0);
}

static __device__ __forceinline__ f32x4 mfma16(bf16x4 a, bf16x4 b, f32x4 c) {
#if __has_builtin(__builtin_amdgcn_mfma_f32_16x16x16_bf16)
  return __builtin_amdgcn_mfma_f32_16x16x16_bf16(a, b, c, 0, 0, 0);
#else
  return __builtin_amdgcn_mfma_f32_16x16x16bf16_1k(a, b, c, 0, 0, 0);
#endif
}

// fast RNE f32->bf16 (no NaN handling; inputs are finite probabilities/sums)
static __device__ __forceinline__ short f2bf(float x) {
  unsigned u = __builtin_bit_cast(unsigned, x);
  u += 0x7FFFu + ((u >> 16) & 1u);
  return (short)(u >> 16);
}

static __device__ __forceinline__ float fexp2(float x) {
#if __has_builtin(__builtin_amdgcn_exp2f)
  return __builtin_amdgcn_exp2f(x);
#else
  return exp2f(x);
#endif
}

// ---------------------------------------------------------------------------
// fp32 -> bf16 elementwise cast
// ---------------------------------------------------------------------------
__global__ void cast_bf16_kernel(const float* __restrict__ in, bf16* __restrict__ out, int n) {
  int i = (blockIdx.x * 256 + threadIdx.x) * 4;
  if (i >= n) return;
  float4 v = *(const float4*)(in + i);
  out[i + 0] = __float2bfloat16(v.x);
  out[i + 1] = __float2bfloat16(v.y);
  out[i + 2] = __float2bfloat16(v.z);
  out[i + 3] = __float2bfloat16(v.w);
}

// ---------------------------------------------------------------------------
// fp32 [R][Ccols] -> bf16 out[Ccols][R]
// ---------------------------------------------------------------------------
__global__ __launch_bounds__(256) void transpose_cast(const float* __restrict__ in,
                                                      bf16* __restrict__ out,
                                                      int R, int Ccols) {
  __shared__ float t[32][33];
  const int tx = threadIdx.x & 31, ty = threadIdx.x >> 5;
  const int r0 = blockIdx.y * 32, c0 = blockIdx.x * 32;
#pragma unroll
  for (int it = 0; it < 4; ++it)
    t[ty + 8 * it][tx] = in[(size_t)(r0 + ty + 8 * it) * Ccols + c0 + tx];
  __syncthreads();
#pragma unroll
  for (int it = 0; it < 4; ++it)
    out[(size_t)(c0 + ty + 8 * it) * R + r0 + tx] = __float2bfloat16(t[tx][ty + 8 * it]);
}

// ---------------------------------------------------------------------------
// v half of qkv -> vt[((b*KVH+kvh)*HD + hd)*T + t]
// ---------------------------------------------------------------------------
__global__ __launch_bounds__(256) void transpose_v(const bf16* __restrict__ qkv,
                                                   bf16* __restrict__ vt) {
  __shared__ bf16 t[32][33];
  const int tx = threadIdx.x & 31, ty = threadIdx.x >> 5;
  const int b = blockIdx.z >> 2, kvh = blockIdx.z & 3;
  const int t0 = blockIdx.x * 32, d0 = blockIdx.y * 32;
#pragma unroll
  for (int it = 0; it < 4; ++it)
    t[ty + 8 * it][tx] =
        qkv[(size_t)(b * T_ + t0 + ty + 8 * it) * NQKV + VOFF + kvh * HD_ + d0 + tx];
  __syncthreads();
#pragma unroll
  for (int it = 0; it < 4; ++it)
    vt[((size_t)((b * KVH_ + kvh) * HD_) + d0 + ty + 8 * it) * T_ + t0 + tx] =
        t[tx][ty + 8 * it];
}

// ---------------------------------------------------------------------------
// RoPE in place on bf16 head-rows inside qkv.
// ---------------------------------------------------------------------------
__global__ void rope_bf16(bf16* __restrict__ buf, int ld, int col0, int nheads) {
  const int row = blockIdx.x / nheads;
  const int h = blockIdx.x % nheads;
  const int t = row % T_;
  const int d = threadIdx.x;
  bf16* rp = buf + (size_t)row * ld + col0 + h * HD_;
  float vd = __bfloat162float(rp[d]);
  float vp = __bfloat162float(rp[d ^ 64]);
  __syncthreads();
  const int i = d & 63;
  float invf = expf(-(float)(2 * i) * (9.210340371976184f / 128.0f));
  float ang = (float)t * invf;
  float c = cosf(ang), s = sinf(ang);
  rp[d] = __float2bfloat16((d < 64) ? (vd * c - vp * s) : (vd * c + vp * s));
}

// ---------------------------------------------------------------------------
// bf16 MFMA GEMM (m97 structure): C[M,N] = A[M,K] @ Bt[N,K]^T (+ bias)
// ---------------------------------------------------------------------------
template <bool BF16OUT>
__global__ __launch_bounds__(256, 2) void gemm_mfma(
    const bf16* __restrict__ A, const bf16* __restrict__ Bt, void* __restrict__ Cout,
    const float* __restrict__ bq, const float* __restrict__ bk2,
    const float* __restrict__ bv2, int M, int N, int K) {
  __shared__ __align__(16) bf16 As[128 * 32];
  __shared__ __align__(16) bf16 Bs[128 * 32];
  const int tid = threadIdx.x;
  const int w = tid >> 6, lane = tid & 63;
  const int colL = lane & 15, quad = lane >> 4;
  const int wm = w & 1, wn = w >> 1;
  const int r0 = blockIdx.y * 128, c0 = blockIdx.x * 128;

  f32x4 acc[4][4];
  const f32x4 zero = {0.f, 0.f, 0.f, 0.f};
#pragma unroll
  for (int mt = 0; mt < 4; ++mt)
#pragma unroll
    for (int nt = 0; nt < 4; ++nt) acc[mt][nt] = zero;

  for (int k0 = 0; k0 < K; k0 += 32) {
    __syncthreads();
#pragma unroll
    for (int it = 0; it < 2; ++it) {
      const int seg = it * 4 + w;
      const int idx = seg * 64 + lane;
      const int row = idx >> 2, off = idx & 3;
      gload_lds16(A + (size_t)(r0 + row) * K + k0 + off * 8, &As[seg * 512]);
      gload_lds16(Bt + (size_t)(c0 + row) * K + k0 + off * 8, &Bs[seg * 512]);
    }
    __syncthreads();
    bf16x8 af[4], bfv[4];
#pragma unroll
    for (int mt = 0; mt < 4; ++mt)
      af[mt] = *(const bf16x8*)&As[(wm * 64 + mt * 16 + colL) * 32 + quad * 8];
#pragma unroll
    for (int nt = 0; nt < 4; ++nt)
      bfv[nt] = *(const bf16x8*)&Bs[(wn * 64 + nt * 16 + colL) * 32 + quad * 8];
#pragma unroll
    for (int mt = 0; mt < 4; ++mt)
#pragma unroll
      for (int nt = 0; nt < 4; ++nt)
        acc[mt][nt] =
            __builtin_amdgcn_mfma_f32_16x16x32_bf16(af[mt], bfv[nt], acc[mt][nt], 0, 0, 0);
  }

#pragma unroll
  for (int nt = 0; nt < 4; ++nt) {
    const int c = c0 + wn * 64 + nt * 16 + colL;
    float bias = 0.f;
    if (bq) bias = (c < KOFF) ? bq[c] : (c < VOFF ? bk2[c - KOFF] : bv2[c - VOFF]);
#pragma unroll
    for (int mt = 0; mt < 4; ++mt) {
#pragma unroll
      for (int i = 0; i < 4; ++i) {
        const int r = r0 + wm * 64 + mt * 16 + quad * 4 + i;
        const float v = acc[mt][nt][i] + bias;
        if (BF16OUT)
          ((bf16*)Cout)[(size_t)r * N + c] = __float2bfloat16(v);
        else
          ((float*)Cout)[(size_t)r * N + c] = v;
      }
    }
  }
}

// ---------------------------------------------------------------------------
// Causal GQA flash attention v4.
// Block = 256 thr = 4 waves; wave w owns q rows [q0+32w, q0+32w+32) completely
// (no parity split, no merge). All waves compute ALL kv tiles of the block's
// shared K/V double buffer (32KB LDS total), so each iteration's compute hides
// its own prefetch latency; barrier only recycles buffers.
// Q in registers (qf[2][4]); transposed math (verified r3): S^T = K·Q^T,
// O^T = V^T·P^T with P in registers; fixed-max softmax (exact shift-invariance).
// Grid: 512 1D blocks, snake qt mapping so consecutive-ID groups (same XCD)
// carry near-constant total work.
// ---------------------------------------------------------------------------
#define FA_SCL2 (0.08838834764831845f * 1.4426950408889634f)  // scale * log2(e)
#define FA_M2 16.0f                                           // fixed max (exp2 domain)

__global__ __launch_bounds__(256, 2) void flash_mfma4(
    const bf16* __restrict__ qkv, const bf16* __restrict__ vt, bf16* __restrict__ ao) {
  __shared__ __align__(16) char smem[32768];
  bf16* Kb0 = (bf16*)smem;                 // 8KB [32 key][128 hd] swz
  bf16* Kb1 = (bf16*)(smem + 8192);        // 8KB
  bf16* Vb0 = (bf16*)(smem + 16384);       // 8KB [128 hd][32 key] swz
  bf16* Vb1 = (bf16*)(smem + 24576);       // 8KB

  const int id = blockIdx.x;
  const int hb = id >> 4;                  // 0..31 = b*16 + h
  const int qq = id & 15;
  const int qt = (hb & 1) ? (15 - qq) : qq;  // snake: balances work per ID-group
  const int h = hb & 15, b = hb >> 4;
  const int kvh = h >> 2;
  const int q0 = qt * 128;

  const int tid = threadIdx.x;
  const int w = tid >> 6, lane = tid & 63;
  const int colL = lane & 15, quad = lane >> 4;
  const int myq0 = q0 + w * 32;            // this wave's 32-row q base (global)

  const bf16* kg = qkv + (size_t)(b * T_) * NQKV + KOFF + kvh * HD_;
  const bf16* vg = vt + (size_t)((b * KVH_ + kvh) * HD_) * T_;

  // stage one 32-key KV tile; wave w stages segs 2w, 2w+1 of each (4 gloads)
  auto stageKV = [&](int tile, bf16* kl, bf16* vl) {
    const int s0k = tile * 32;
#pragma unroll
    for (int j = 0; j < 2; ++j) {
      const int s = 2 * w + j;
      const int row = s * 4 + quad;              // key 0..31
      const int g = colL ^ (row & 7);
      gload_lds16(kg + (size_t)(s0k + row) * NQKV + g * 8, kl + s * 512);
    }
#pragma unroll
    for (int j = 0; j < 2; ++j) {
      const int s = 2 * w + j;
      const int row = s * 16 + (lane >> 2);      // hd 0..127
      const int g = (lane & 3) ^ ((row >> 1) & 3);
      gload_lds16(vg + (size_t)row * T_ + s0k + g * 8, vl + s * 512);
    }
  };

  // Q fragments in registers (B-operand of K·Q^T): q row = myq0+mq*16+colL
  bf16x8 qf[2][4];
  {
    const bf16* qgw = qkv + (size_t)(b * T_ + myq0) * NQKV + h * HD_;
#pragma unroll
    for (int mq = 0; mq < 2; ++mq)
#pragma unroll
      for (int c = 0; c < 4; ++c)
        qf[mq][c] = *(const bf16x8*)(qgw + (size_t)(mq * 16 + colL) * NQKV + c * 32 + quad * 8);
  }

  f32x4 o[2][8];  // O^T: lane holds (hd = ht*16 + quad*4 + i, q = myq0 + mq*16 + colL)
  const f32x4 zero = {0.f, 0.f, 0.f, 0.f};
#pragma unroll
  for (int mq = 0; mq < 2; ++mq)
#pragma unroll
    for (int ht = 0; ht < 8; ++ht) o[mq][ht] = zero;
  float l_[2] = {0.f, 0.f};

  const int nkv = 4 * qt + 4;
  stageKV(0, Kb0, Vb0);
  asm volatile("s_waitcnt vmcnt(0)\n\ts_barrier" ::: "memory");

  for (int tt = 0; tt < nkv; ++tt) {
    const bf16* Ks = (tt & 1) ? Kb1 : Kb0;
    const bf16* Vs = (tt & 1) ? Vb1 : Vb0;
    if (tt + 1 < nkv) stageKV(tt + 1, (tt & 1) ? Kb0 : Kb1, (tt & 1) ? Vb0 : Vb1);

    const int s0 = tt * 32;
    if (s0 < myq0 + 32) {  // not fully masked for this wave
      // S^T = K · Q^T
      f32x4 s_[2][2];
      s_[0][0] = zero; s_[0][1] = zero; s_[1][0] = zero; s_[1][1] = zero;
#pragma unroll
      for (int c = 0; c < 4; ++c) {
        const int ch = ((c * 4 + quad) ^ (colL & 7)) * 8;
        bf16x8 kf0 = *(const bf16x8*)(Ks + (size_t)colL * 128 + ch);
        bf16x8 kf1 = *(const bf16x8*)(Ks + (size_t)(16 + colL) * 128 + ch);
#pragma unroll
        for (int mq = 0; mq < 2; ++mq) {
          s_[0][mq] = __builtin_amdgcn_mfma_f32_16x16x32_bf16(kf0, qf[mq][c], s_[0][mq], 0, 0, 0);
          s_[1][mq] = __builtin_amdgcn_mfma_f32_16x16x32_bf16(kf1, qf[mq][c], s_[1][mq], 0, 0, 0);
        }
      }

      // p = exp2(s*scale*log2e - M2); mask only diagonal-straddling tiles
      bf16x4 pf[2][2];
      if (s0 >= myq0) {
#pragma unroll
        for (int kt = 0; kt < 2; ++kt)
#pragma unroll
          for (int mq = 0; mq < 2; ++mq) {
            const int qcol = myq0 + mq * 16 + colL;
            const int kb = s0 + kt * 16 + quad * 4;
            float pv[4];
#pragma unroll
            for (int i = 0; i < 4; ++i) {
              float e = fexp2(fmaf(s_[kt][mq][i], FA_SCL2, -FA_M2));
              pv[i] = (kb + i <= qcol) ? e : 0.f;
            }
            l_[mq] += (pv[0] + pv[1]) + (pv[2] + pv[3]);
            pf[kt][mq] = (bf16x4){f2bf(pv[0]), f2bf(pv[1]), f2bf(pv[2]), f2bf(pv[3])};
          }
      } else {
#pragma unroll
        for (int kt = 0; kt < 2; ++kt)
#pragma unroll
          for (int mq = 0; mq < 2; ++mq) {
            float pv[4];
#pragma unroll
            for (int i = 0; i < 4; ++i)
              pv[i] = fexp2(fmaf(s_[kt][mq][i], FA_SCL2, -FA_M2));
            l_[mq] += (pv[0] + pv[1]) + (pv[2] + pv[3]);
            pf[kt][mq] = (bf16x4){f2bf(pv[0]), f2bf(pv[1]), f2bf(pv[2]), f2bf(pv[3])};
          }
      }

      // O^T += V^T · P^T (P stays in registers)
#pragma unroll
      for (int ht = 0; ht < 8; ++ht) {
        const int row = ht * 16 + colL;
#pragma unroll
        for (int kt = 0; kt < 2; ++kt) {
          bf16x4 vf = *(const bf16x4*)(Vs + (size_t)row * 32 +
                                       (((kt * 2 + (quad >> 1)) ^ ((row >> 1) & 3)) * 8) +
                                       (quad & 1) * 4);
#pragma unroll
          for (int mq = 0; mq < 2; ++mq) o[mq][ht] = mfma16(vf, pf[kt][mq], o[mq][ht]);
        }
      }
    }
    // own staging loads (issued one compute-phase ago) done + buffer recycle sync
    asm volatile("s_waitcnt vmcnt(0)\n\ts_barrier" ::: "memory");
  }

  // epilogue: reduce l over key-quads, scale, direct store (no merge needed)
#pragma unroll
  for (int mq = 0; mq < 2; ++mq) {
    l_[mq] += __shfl_xor(l_[mq], 16);
    l_[mq] += __shfl_xor(l_[mq], 32);
    const float rl = 1.f / l_[mq];
    const size_t rbase = (size_t)(b * T_ + myq0 + mq * 16 + colL) * (H_ * HD_) + h * HD_;
#pragma unroll
    for (int ht = 0; ht < 8; ++ht) {
      bf16x4 ov;
#pragma unroll
      for (int i = 0; i < 4; ++i) ov[i] = f2bf(o[mq][ht][i] * rl);
      *(bf16x4*)(ao + rbase + ht * 16 + quad * 4) = ov;
    }
  }
}

// ---------------------------------------------------------------------------
extern "C" void kernel_launch(void* const* d_in, const int* in_sizes, int n_in,
                              void* d_out, int out_size, void* d_ws, size_t ws_size,
                              hipStream_t stream) {
  (void)in_sizes; (void)n_in; (void)out_size; (void)ws_size;
  const float* x  = (const float*)d_in[0];
  const float* wq = (const float*)d_in[1];
  const float* bq = (const float*)d_in[2];
  const float* wk = (const float*)d_in[3];
  const float* bk = (const float*)d_in[4];
  const float* wv = (const float*)d_in[5];
  const float* bv = (const float*)d_in[6];
  const float* wo = (const float*)d_in[7];
  float* out = (float*)d_out;

  char* ws = (char*)d_ws;
  bf16* xb    = (bf16*)ws;                 // 16 MiB; reused as ao after QKV gemm
  bf16* wqkvT = (bf16*)(ws + (16u << 20)); // 12 MiB [3072][2048]
  bf16* woT   = (bf16*)(ws + (28u << 20)); //  8 MiB [2048][2048]
  bf16* qkv   = (bf16*)(ws + (36u << 20)); // 24 MiB [4096][3072]
  bf16* vt    = (bf16*)(ws + (60u << 20)); //  4 MiB [1024][2048]

  cast_bf16_kernel<<<dim3(MROWS * C_ / 1024), dim3(256), 0, stream>>>(x, xb, MROWS * C_);

  transpose_cast<<<dim3(64, 64), dim3(256), 0, stream>>>(wq, wqkvT, C_, 2048);
  transpose_cast<<<dim3(16, 64), dim3(256), 0, stream>>>(wk, wqkvT + (size_t)KOFF * C_, C_, 512);
  transpose_cast<<<dim3(16, 64), dim3(256), 0, stream>>>(wv, wqkvT + (size_t)VOFF * C_, C_, 512);
  transpose_cast<<<dim3(64, 64), dim3(256), 0, stream>>>(wo, woT, 2048, 2048);

  gemm_mfma<true><<<dim3(NQKV / 128, MROWS / 128), dim3(256), 0, stream>>>(
      xb, wqkvT, qkv, bq, bk, bv, MROWS, NQKV, C_);

  rope_bf16<<<dim3(MROWS * H_), dim3(128), 0, stream>>>(qkv, NQKV, 0, H_);
  rope_bf16<<<dim3(MROWS * KVH_), dim3(128), 0, stream>>>(qkv, NQKV, KOFF, KVH_);

  transpose_v<<<dim3(T_ / 32, HD_ / 32, B_ * KVH_), dim3(256), 0, stream>>>(qkv, vt);

  bf16* ao = xb;
  flash_mfma4<<<dim3(512), dim3(256), 0, stream>>>(qkv, vt, ao);

  gemm_mfma<false><<<dim3(C_ / 128, MROWS / 128), dim3(256), 0, stream>>>(
      ao, woT, out, nullptr, nullptr, nullptr, MROWS, C_, KOFF);
}

// Round 6
// 354.109 us; speedup vs baseline: 1.1407x; 1.0132x over previous
//
#include <hip/hip_runtime.h>
#include <hip/hip_bf16.h>
#include <math.h>

#define B_ 2
#define T_ 2048
#define C_ 2048
#define H_ 16
#define KVH_ 4
#define HD_ 128
#define G_ (H_ / KVH_)
#define MROWS (B_ * T_)                    // 4096
#define NQKV (H_ * HD_ + 2 * KVH_ * HD_)   // 3072
#define KOFF (H_ * HD_)                    // 2048
#define VOFF (H_ * HD_ + KVH_ * HD_)       // 2560

typedef __hip_bfloat16 bf16;
typedef short bf16x8 __attribute__((ext_vector_type(8)));   // 8 bf16 = 4 VGPR
typedef short bf16x4 __attribute__((ext_vector_type(4)));   // 4 bf16 = 2 VGPR
typedef float f32x4 __attribute__((ext_vector_type(4)));

__device__ __forceinline__ void gload_lds16(const void* g, void* l) {
  __builtin_amdgcn_global_load_lds(
      (const __attribute__((address_space(1))) unsigned int*)g,
      (__attribute__((address_space(3))) unsigned int*)l, 16, 0, 0);
}

static __device__ __forceinline__ f32x4 mfma16(bf16x4 a, bf16x4 b, f32x4 c) {
#if __has_builtin(__builtin_amdgcn_mfma_f32_16x16x16_bf16)
  return __builtin_amdgcn_mfma_f32_16x16x16_bf16(a, b, c, 0, 0, 0);
#else
  return __builtin_amdgcn_mfma_f32_16x16x16bf16_1k(a, b, c, 0, 0, 0);
#endif
}

// fast RNE f32->bf16 (no NaN handling; inputs are finite probabilities/sums)
static __device__ __forceinline__ short f2bf(float x) {
  unsigned u = __builtin_bit_cast(unsigned, x);
  u += 0x7FFFu + ((u >> 16) & 1u);
  return (short)(u >> 16);
}

static __device__ __forceinline__ float fexp2(float x) {
#if __has_builtin(__builtin_amdgcn_exp2f)
  return __builtin_amdgcn_exp2f(x);
#else
  return exp2f(x);
#endif
}

// ---------------------------------------------------------------------------
// fp32 -> bf16 elementwise cast
// ---------------------------------------------------------------------------
__global__ void cast_bf16_kernel(const float* __restrict__ in, bf16* __restrict__ out, int n) {
  int i = (blockIdx.x * 256 + threadIdx.x) * 4;
  if (i >= n) return;
  float4 v = *(const float4*)(in + i);
  out[i + 0] = __float2bfloat16(v.x);
  out[i + 1] = __float2bfloat16(v.y);
  out[i + 2] = __float2bfloat16(v.z);
  out[i + 3] = __float2bfloat16(v.w);
}

// ---------------------------------------------------------------------------
// fp32 [R][Ccols] -> bf16 out[Ccols][R]  (for wo)
// ---------------------------------------------------------------------------
__global__ __launch_bounds__(256) void transpose_cast(const float* __restrict__ in,
                                                      bf16* __restrict__ out,
                                                      int R, int Ccols) {
  __shared__ float t[32][33];
  const int tx = threadIdx.x & 31, ty = threadIdx.x >> 5;
  const int r0 = blockIdx.y * 32, c0 = blockIdx.x * 32;
#pragma unroll
  for (int it = 0; it < 4; ++it)
    t[ty + 8 * it][tx] = in[(size_t)(r0 + ty + 8 * it) * Ccols + c0 + tx];
  __syncthreads();
#pragma unroll
  for (int it = 0; it < 4; ++it)
    out[(size_t)(c0 + ty + 8 * it) * R + r0 + tx] = __float2bfloat16(t[tx][ty + 8 * it]);
}

// ---------------------------------------------------------------------------
// Fused wq|wk|wv [2048][*] -> wqkvT [3072][2048] transpose-cast (1 launch)
// ---------------------------------------------------------------------------
__global__ __launch_bounds__(256) void transpose_cast_qkvw(
    const float* __restrict__ wq, const float* __restrict__ wk,
    const float* __restrict__ wv, bf16* __restrict__ outT) {
  __shared__ float t[32][33];
  const int tx = threadIdx.x & 31, ty = threadIdx.x >> 5;
  const int r0 = blockIdx.y * 32;           // k-dim
  const int c0 = blockIdx.x * 32;           // fused n-dim 0..3071
  const float* src;
  int nn, ld;
  if (c0 < KOFF)      { src = wq; nn = c0;        ld = 2048; }
  else if (c0 < VOFF) { src = wk; nn = c0 - KOFF; ld = 512; }
  else                { src = wv; nn = c0 - VOFF; ld = 512; }
#pragma unroll
  for (int it = 0; it < 4; ++it)
    t[ty + 8 * it][tx] = src[(size_t)(r0 + ty + 8 * it) * ld + nn + tx];
  __syncthreads();
#pragma unroll
  for (int it = 0; it < 4; ++it)
    outT[(size_t)(c0 + ty + 8 * it) * 2048 + r0 + tx] = __float2bfloat16(t[tx][ty + 8 * it]);
}

// ---------------------------------------------------------------------------
// v half of qkv -> vt[((b*KVH+kvh)*HD + hd)*T + t]
// ---------------------------------------------------------------------------
__global__ __launch_bounds__(256) void transpose_v(const bf16* __restrict__ qkv,
                                                   bf16* __restrict__ vt) {
  __shared__ bf16 t[32][33];
  const int tx = threadIdx.x & 31, ty = threadIdx.x >> 5;
  const int b = blockIdx.z >> 2, kvh = blockIdx.z & 3;
  const int t0 = blockIdx.x * 32, d0 = blockIdx.y * 32;
#pragma unroll
  for (int it = 0; it < 4; ++it)
    t[ty + 8 * it][tx] =
        qkv[(size_t)(b * T_ + t0 + ty + 8 * it) * NQKV + VOFF + kvh * HD_ + d0 + tx];
  __syncthreads();
#pragma unroll
  for (int it = 0; it < 4; ++it)
    vt[((size_t)((b * KVH_ + kvh) * HD_) + d0 + ty + 8 * it) * T_ + t0 + tx] =
        t[tx][ty + 8 * it];
}

// ---------------------------------------------------------------------------
// RoPE in place on bf16 head-rows inside qkv (fast sincos).
// ---------------------------------------------------------------------------
__global__ void rope_bf16(bf16* __restrict__ buf, int ld, int col0, int nheads) {
  const int row = blockIdx.x / nheads;
  const int h = blockIdx.x % nheads;
  const int t = row % T_;
  const int d = threadIdx.x;
  bf16* rp = buf + (size_t)row * ld + col0 + h * HD_;
  float vd = __bfloat162float(rp[d]);
  float vp = __bfloat162float(rp[d ^ 64]);
  __syncthreads();
  const int i = d & 63;
  // invf = 10000^(-2i/128) = exp2(-i * log2(10000)/64)
  float invf = fexp2(-(float)i * (13.287712379549449f / 64.0f));
  float ang = (float)t * invf;
  float s, c;
  __sincosf(ang, &s, &c);
  rp[d] = __float2bfloat16((d < 64) ? (vd * c - vp * s) : (vd * c + vp * s));
}

// ---------------------------------------------------------------------------
// bf16 MFMA GEMM (m97 structure): C[M,N] = A[M,K] @ Bt[N,K]^T (+ bias)
// ---------------------------------------------------------------------------
template <bool BF16OUT>
__global__ __launch_bounds__(256, 2) void gemm_mfma(
    const bf16* __restrict__ A, const bf16* __restrict__ Bt, void* __restrict__ Cout,
    const float* __restrict__ bq, const float* __restrict__ bk2,
    const float* __restrict__ bv2, int M, int N, int K) {
  __shared__ __align__(16) bf16 As[128 * 32];
  __shared__ __align__(16) bf16 Bs[128 * 32];
  const int tid = threadIdx.x;
  const int w = tid >> 6, lane = tid & 63;
  const int colL = lane & 15, quad = lane >> 4;
  const int wm = w & 1, wn = w >> 1;
  const int r0 = blockIdx.y * 128, c0 = blockIdx.x * 128;

  f32x4 acc[4][4];
  const f32x4 zero = {0.f, 0.f, 0.f, 0.f};
#pragma unroll
  for (int mt = 0; mt < 4; ++mt)
#pragma unroll
    for (int nt = 0; nt < 4; ++nt) acc[mt][nt] = zero;

  for (int k0 = 0; k0 < K; k0 += 32) {
    __syncthreads();
#pragma unroll
    for (int it = 0; it < 2; ++it) {
      const int seg = it * 4 + w;
      const int idx = seg * 64 + lane;
      const int row = idx >> 2, off = idx & 3;
      gload_lds16(A + (size_t)(r0 + row) * K + k0 + off * 8, &As[seg * 512]);
      gload_lds16(Bt + (size_t)(c0 + row) * K + k0 + off * 8, &Bs[seg * 512]);
    }
    __syncthreads();
    bf16x8 af[4], bfv[4];
#pragma unroll
    for (int mt = 0; mt < 4; ++mt)
      af[mt] = *(const bf16x8*)&As[(wm * 64 + mt * 16 + colL) * 32 + quad * 8];
#pragma unroll
    for (int nt = 0; nt < 4; ++nt)
      bfv[nt] = *(const bf16x8*)&Bs[(wn * 64 + nt * 16 + colL) * 32 + quad * 8];
#pragma unroll
    for (int mt = 0; mt < 4; ++mt)
#pragma unroll
      for (int nt = 0; nt < 4; ++nt)
        acc[mt][nt] =
            __builtin_amdgcn_mfma_f32_16x16x32_bf16(af[mt], bfv[nt], acc[mt][nt], 0, 0, 0);
  }

#pragma unroll
  for (int nt = 0; nt < 4; ++nt) {
    const int c = c0 + wn * 64 + nt * 16 + colL;
    float bias = 0.f;
    if (bq) bias = (c < KOFF) ? bq[c] : (c < VOFF ? bk2[c - KOFF] : bv2[c - VOFF]);
#pragma unroll
    for (int mt = 0; mt < 4; ++mt) {
#pragma unroll
      for (int i = 0; i < 4; ++i) {
        const int r = r0 + wm * 64 + mt * 16 + quad * 4 + i;
        const float v = acc[mt][nt][i] + bias;
        if (BF16OUT)
          ((bf16*)Cout)[(size_t)r * N + c] = __float2bfloat16(v);
        else
          ((float*)Cout)[(size_t)r * N + c] = v;
      }
    }
  }
}

// ---------------------------------------------------------------------------
// Causal GQA flash attention v5.
// Block = 128 thr = 2 waves; wave w owns q rows [q0+32w, q0+32w+32).
// Shared K/V double buffer 32KB; grid 1024 blocks -> 5 blocks/CU (LDS-limited),
// ~10 waves/CU resident for cross-block latency hiding. Snake qt mapping
// interleaves heavy/light blocks in consecutive IDs.
// Transposed math (verified r3): S^T = K*Q^T; O^T = V^T*P^T, P in registers;
// fixed-max softmax (exact by shift-invariance).
// ---------------------------------------------------------------------------
#define FA_SCL2 (0.08838834764831845f * 1.4426950408889634f)  // scale * log2(e)
#define FA_M2 16.0f                                           // fixed max (exp2 domain)

__global__ __launch_bounds__(128, 2) void flash_mfma5(
    const bf16* __restrict__ qkv, const bf16* __restrict__ vt, bf16* __restrict__ ao) {
  __shared__ __align__(16) char smem[32768];
  bf16* Kb0 = (bf16*)smem;                 // 8KB [32 key][128 hd] swz
  bf16* Kb1 = (bf16*)(smem + 8192);        // 8KB
  bf16* Vb0 = (bf16*)(smem + 16384);       // 8KB [128 hd][32 key] swz
  bf16* Vb1 = (bf16*)(smem + 24576);       // 8KB

  const int id = blockIdx.x;
  const int hb = id >> 5;                  // 0..31 = b*16 + h
  const int qq = id & 31;
  const int qt = (qq & 1) ? (qq >> 1) : (31 - (qq >> 1));  // interleave heavy/light
  const int h = hb & 15, b = hb >> 4;
  const int kvh = h >> 2;

  const int tid = threadIdx.x;
  const int w = tid >> 6, lane = tid & 63;
  const int colL = lane & 15, quad = lane >> 4;
  const int myq0 = qt * 64 + 32 * w;       // this wave's 32-row q base (global)

  const bf16* kg = qkv + (size_t)(b * T_) * NQKV + KOFF + kvh * HD_;
  const bf16* vg = vt + (size_t)((b * KVH_ + kvh) * HD_) * T_;

  // stage one 32-key KV tile; wave w stages segs 4w..4w+3 of each (8 gloads)
  auto stageKV = [&](int tile, bf16* kl, bf16* vl) {
    const int s0k = tile * 32;
#pragma unroll
    for (int j = 0; j < 4; ++j) {
      const int s = 4 * w + j;
      const int row = s * 4 + quad;              // key 0..31
      const int g = colL ^ (row & 7);
      gload_lds16(kg + (size_t)(s0k + row) * NQKV + g * 8, kl + s * 512);
    }
#pragma unroll
    for (int j = 0; j < 4; ++j) {
      const int s = 4 * w + j;
      const int row = s * 16 + (lane >> 2);      // hd 0..127
      const int g = (lane & 3) ^ ((row >> 1) & 3);
      gload_lds16(vg + (size_t)row * T_ + s0k + g * 8, vl + s * 512);
    }
  };

  // Q fragments in registers (B-operand of K·Q^T): q row = myq0+mq*16+colL
  bf16x8 qf[2][4];
  {
    const bf16* qgw = qkv + (size_t)(b * T_ + myq0) * NQKV + h * HD_;
#pragma unroll
    for (int mq = 0; mq < 2; ++mq)
#pragma unroll
      for (int c = 0; c < 4; ++c)
        qf[mq][c] = *(const bf16x8*)(qgw + (size_t)(mq * 16 + colL) * NQKV + c * 32 + quad * 8);
  }

  f32x4 o[2][8];  // O^T: lane holds (hd = ht*16 + quad*4 + i, q = myq0 + mq*16 + colL)
  const f32x4 zero = {0.f, 0.f, 0.f, 0.f};
#pragma unroll
  for (int mq = 0; mq < 2; ++mq)
#pragma unroll
    for (int ht = 0; ht < 8; ++ht) o[mq][ht] = zero;
  float l_[2] = {0.f, 0.f};

  const int nkv = 2 * qt + 2;
  stageKV(0, Kb0, Vb0);
  asm volatile("s_waitcnt vmcnt(0)\n\ts_barrier" ::: "memory");

  for (int tt = 0; tt < nkv; ++tt) {
    const bf16* Ks = (tt & 1) ? Kb1 : Kb0;
    const bf16* Vs = (tt & 1) ? Vb1 : Vb0;
    if (tt + 1 < nkv) stageKV(tt + 1, (tt & 1) ? Kb0 : Kb1, (tt & 1) ? Vb0 : Vb1);

    const int s0 = tt * 32;
    if (s0 < myq0 + 32) {  // not fully masked for this wave
      // S^T = K · Q^T
      f32x4 s_[2][2];
      s_[0][0] = zero; s_[0][1] = zero; s_[1][0] = zero; s_[1][1] = zero;
#pragma unroll
      for (int c = 0; c < 4; ++c) {
        const int ch = ((c * 4 + quad) ^ (colL & 7)) * 8;
        bf16x8 kf0 = *(const bf16x8*)(Ks + (size_t)colL * 128 + ch);
        bf16x8 kf1 = *(const bf16x8*)(Ks + (size_t)(16 + colL) * 128 + ch);
#pragma unroll
        for (int mq = 0; mq < 2; ++mq) {
          s_[0][mq] = __builtin_amdgcn_mfma_f32_16x16x32_bf16(kf0, qf[mq][c], s_[0][mq], 0, 0, 0);
          s_[1][mq] = __builtin_amdgcn_mfma_f32_16x16x32_bf16(kf1, qf[mq][c], s_[1][mq], 0, 0, 0);
        }
      }

      // p = exp2(s*scale*log2e - M2); mask only diagonal-straddling tiles
      bf16x4 pf[2][2];
      if (s0 >= myq0) {
#pragma unroll
        for (int kt = 0; kt < 2; ++kt)
#pragma unroll
          for (int mq = 0; mq < 2; ++mq) {
            const int qcol = myq0 + mq * 16 + colL;
            const int kb = s0 + kt * 16 + quad * 4;
            float pv[4];
#pragma unroll
            for (int i = 0; i < 4; ++i) {
              float e = fexp2(fmaf(s_[kt][mq][i], FA_SCL2, -FA_M2));
              pv[i] = (kb + i <= qcol) ? e : 0.f;
            }
            l_[mq] += (pv[0] + pv[1]) + (pv[2] + pv[3]);
            pf[kt][mq] = (bf16x4){f2bf(pv[0]), f2bf(pv[1]), f2bf(pv[2]), f2bf(pv[3])};
          }
      } else {
#pragma unroll
        for (int kt = 0; kt < 2; ++kt)
#pragma unroll
          for (int mq = 0; mq < 2; ++mq) {
            float pv[4];
#pragma unroll
            for (int i = 0; i < 4; ++i)
              pv[i] = fexp2(fmaf(s_[kt][mq][i], FA_SCL2, -FA_M2));
            l_[mq] += (pv[0] + pv[1]) + (pv[2] + pv[3]);
            pf[kt][mq] = (bf16x4){f2bf(pv[0]), f2bf(pv[1]), f2bf(pv[2]), f2bf(pv[3])};
          }
      }

      // O^T += V^T · P^T (P stays in registers)
#pragma unroll
      for (int ht = 0; ht < 8; ++ht) {
        const int row = ht * 16 + colL;
#pragma unroll
        for (int kt = 0; kt < 2; ++kt) {
          bf16x4 vf = *(const bf16x4*)(Vs + (size_t)row * 32 +
                                       (((kt * 2 + (quad >> 1)) ^ ((row >> 1) & 3)) * 8) +
                                       (quad & 1) * 4);
#pragma unroll
          for (int mq = 0; mq < 2; ++mq) o[mq][ht] = mfma16(vf, pf[kt][mq], o[mq][ht]);
        }
      }
    }
    // own staging loads (issued one compute-phase ago) done + buffer recycle sync
    asm volatile("s_waitcnt vmcnt(0)\n\ts_barrier" ::: "memory");
  }

  // epilogue: reduce l over key-quads, scale, direct store (no merge needed)
#pragma unroll
  for (int mq = 0; mq < 2; ++mq) {
    l_[mq] += __shfl_xor(l_[mq], 16);
    l_[mq] += __shfl_xor(l_[mq], 32);
    const float rl = 1.f / l_[mq];
    const size_t rbase = (size_t)(b * T_ + myq0 + mq * 16 + colL) * (H_ * HD_) + h * HD_;
#pragma unroll
    for (int ht = 0; ht < 8; ++ht) {
      bf16x4 ov;
#pragma unroll
      for (int i = 0; i < 4; ++i) ov[i] = f2bf(o[mq][ht][i] * rl);
      *(bf16x4*)(ao + rbase + ht * 16 + quad * 4) = ov;
    }
  }
}

// ---------------------------------------------------------------------------
extern "C" void kernel_launch(void* const* d_in, const int* in_sizes, int n_in,
                              void* d_out, int out_size, void* d_ws, size_t ws_size,
                              hipStream_t stream) {
  (void)in_sizes; (void)n_in; (void)out_size; (void)ws_size;
  const float* x  = (const float*)d_in[0];
  const float* wq = (const float*)d_in[1];
  const float* bq = (const float*)d_in[2];
  const float* wk = (const float*)d_in[3];
  const float* bk = (const float*)d_in[4];
  const float* wv = (const float*)d_in[5];
  const float* bv = (const float*)d_in[6];
  const float* wo = (const float*)d_in[7];
  float* out = (float*)d_out;

  char* ws = (char*)d_ws;
  bf16* xb    = (bf16*)ws;                 // 16 MiB; reused as ao after QKV gemm
  bf16* wqkvT = (bf16*)(ws + (16u << 20)); // 12 MiB [3072][2048]
  bf16* woT   = (bf16*)(ws + (28u << 20)); //  8 MiB [2048][2048]
  bf16* qkv   = (bf16*)(ws + (36u << 20)); // 24 MiB [4096][3072]
  bf16* vt    = (bf16*)(ws + (60u << 20)); //  4 MiB [1024][2048]

  cast_bf16_kernel<<<dim3(MROWS * C_ / 1024), dim3(256), 0, stream>>>(x, xb, MROWS * C_);

  transpose_cast_qkvw<<<dim3(96, 64), dim3(256), 0, stream>>>(wq, wk, wv, wqkvT);
  transpose_cast<<<dim3(64, 64), dim3(256), 0, stream>>>(wo, woT, 2048, 2048);

  gemm_mfma<true><<<dim3(NQKV / 128, MROWS / 128), dim3(256), 0, stream>>>(
      xb, wqkvT, qkv, bq, bk, bv, MROWS, NQKV, C_);

  rope_bf16<<<dim3(MROWS * H_), dim3(128), 0, stream>>>(qkv, NQKV, 0, H_);
  rope_bf16<<<dim3(MROWS * KVH_), dim3(128), 0, stream>>>(qkv, NQKV, KOFF, KVH_);

  transpose_v<<<dim3(T_ / 32, HD_ / 32, B_ * KVH_), dim3(256), 0, stream>>>(qkv, vt);

  bf16* ao = xb;
  flash_mfma5<<<dim3(1024), dim3(128), 0, stream>>>(qkv, vt, ao);

  gemm_mfma<false><<<dim3(C_ / 128, MROWS / 128), dim3(256), 0, stream>>>(
      ao, woT, out, nullptr, nullptr, nullptr, MROWS, C_, KOFF);
}